// Round 4
// baseline (98.622 us; speedup 1.0000x reference)
//
#include <hip/hip_runtime.h>

// Contrast-depth loss:
//   d = out - label   (elementwise, [B,32,32] fp32)
//   loss = mean over (b, 8 neighbors, 30x30 centers) of
//          (d[y+dy][x+dx] - d[y][x])^2, centers y,x in [1,30]
//
// R4 design: fillBuffer-style free-running waves. Wave owns 2 images, lane
// owns one float4 (4 pixels of a row) per 8-row slab; vertical neighbors via
// lane+-8 shuffles, horizontal via lane+-1. No LDS staging, no barriers, no
// per-batch vmcnt(0). Single fused kernel; last block reduces partials in a
// fixed (deterministic) order.

#define THREADS 256

__global__ __launch_bounds__(THREADS, 8) void cdl_fused(
    const float* __restrict__ outp,
    const float* __restrict__ labp,
    float* __restrict__ partial,   // [gridDim.x]
    int* __restrict__ counter,     // zeroed by memsetAsync before launch
    float* __restrict__ out,
    int nimg, float inv_count)
{
    const int t    = threadIdx.x;
    const int lane = t & 63;
    const int wid  = t >> 6;
    const int img0 = (blockIdx.x * 4 + wid) * 2;

    const int cg = lane & 7;    // col group: owns cols 4cg..4cg+3
    const int r  = lane >> 3;   // slab-local row 0..7
    const float w0   = (cg == 0) ? 0.f : 1.f;            // col 0 is not a center
    const float w3   = (cg == 7) ? 0.f : 1.f;            // col 31 is not a center
    const float mrow = (r >= 1 && r <= 6) ? 1.f : 0.f;   // slab edge rows: neighbors only

    float acc = 0.f;

    // slab s covers rows 6s..6s+7 (s=0..4): float4 base = img*256 + s*48 + lane
    const float4* ob = (const float4*)outp + (long long)img0 * 256 + lane;
    const float4* lb = (const float4*)labp + (long long)img0 * 256 + lane;

    #pragma unroll
    for (int im = 0; im < 2; ++im) {
        if (img0 + im < nimg) {       // wave-uniform
            const float4* obase = ob + im * 256;
            const float4* lbase = lb + im * 256;
            #pragma unroll
            for (int s2 = 0; s2 < 5; ++s2) {
                const float4 o = obase[s2 * 48];
                const float4 l = lbase[s2 * 48];
                const float d0 = o.x - l.x, d1 = o.y - l.y,
                            d2 = o.z - l.z, d3 = o.w - l.w;
                // row r-1 (up) and r+1 (down) live in lanes -+8
                const float u0 = __shfl(d0, lane - 8), u1 = __shfl(d1, lane - 8),
                            u2 = __shfl(d2, lane - 8), u3 = __shfl(d3, lane - 8);
                const float v0 = __shfl(d0, lane + 8), v1 = __shfl(d1, lane + 8),
                            v2 = __shfl(d2, lane + 8), v3 = __shfl(d3, lane + 8);
                const float dL = __shfl(d3, lane - 1), dR = __shfl(d0, lane + 1);
                const float uL = __shfl(d3, lane - 9), uR = __shfl(d0, lane - 7);
                const float vL = __shfl(d3, lane + 7), vR = __shfl(d0, lane + 9);
                float s, vv, tot;
                // j=0, center d0 (col 4cg): masked out at cg==0
                s = 0.f;
                vv = uL - d0; s += vv * vv;  vv = u0 - d0; s += vv * vv;
                vv = u1 - d0; s += vv * vv;  vv = dL - d0; s += vv * vv;
                vv = d1 - d0; s += vv * vv;  vv = vL - d0; s += vv * vv;
                vv = v0 - d0; s += vv * vv;  vv = v1 - d0; s += vv * vv;
                tot = w0 * s;
                // j=1, center d1
                s = 0.f;
                vv = u0 - d1; s += vv * vv;  vv = u1 - d1; s += vv * vv;
                vv = u2 - d1; s += vv * vv;  vv = d0 - d1; s += vv * vv;
                vv = d2 - d1; s += vv * vv;  vv = v0 - d1; s += vv * vv;
                vv = v1 - d1; s += vv * vv;  vv = v2 - d1; s += vv * vv;
                tot += s;
                // j=2, center d2
                s = 0.f;
                vv = u1 - d2; s += vv * vv;  vv = u2 - d2; s += vv * vv;
                vv = u3 - d2; s += vv * vv;  vv = d1 - d2; s += vv * vv;
                vv = d3 - d2; s += vv * vv;  vv = v1 - d2; s += vv * vv;
                vv = v2 - d2; s += vv * vv;  vv = v3 - d2; s += vv * vv;
                tot += s;
                // j=3, center d3 (col 4cg+3): masked out at cg==7
                s = 0.f;
                vv = u2 - d3; s += vv * vv;  vv = u3 - d3; s += vv * vv;
                vv = uR - d3; s += vv * vv;  vv = d2 - d3; s += vv * vv;
                vv = dR - d3; s += vv * vv;  vv = v2 - d3; s += vv * vv;
                vv = v3 - d3; s += vv * vv;  vv = vR - d3; s += vv * vv;
                tot += w3 * s;

                acc += mrow * tot;
            }
        }
    }

    // block reduction
    #pragma unroll
    for (int off = 32; off; off >>= 1) acc += __shfl_down(acc, off, 64);
    __shared__ float red[4];
    if (lane == 0) red[wid] = acc;
    __syncthreads();
    if (t == 0) {
        partial[blockIdx.x] = red[0] + red[1] + red[2] + red[3];
        __threadfence();
    }
    __syncthreads();

    // last block to finish reduces all partials in fixed order (deterministic)
    __shared__ int is_last;
    if (t == 0) is_last = (atomicAdd(counter, 1) == (int)gridDim.x - 1) ? 1 : 0;
    __syncthreads();
    if (is_last) {
        __threadfence();
        float a = 0.f;
        for (int i = t; i < (int)gridDim.x; i += THREADS) a += partial[i];
        #pragma unroll
        for (int off = 32; off; off >>= 1) a += __shfl_down(a, off, 64);
        if (lane == 0) red[wid] = a;
        __syncthreads();
        if (t == 0) out[0] = (red[0] + red[1] + red[2] + red[3]) * inv_count;
    }
}

extern "C" void kernel_launch(void* const* d_in, const int* in_sizes, int n_in,
                              void* d_out, int out_size, void* d_ws, size_t ws_size,
                              hipStream_t stream) {
    const float* outp = (const float*)d_in[0];
    const float* labp = (const float*)d_in[1];
    const int nimg = in_sizes[0] / 1024;                 // B (H=W=32)
    const int nblocks = (nimg + 7) / 8;                  // 2 img/wave, 4 waves/block
    const float inv_count = 1.0f / ((float)nimg * 8.0f * 900.0f);

    int* counter = (int*)d_ws;                           // [0]: arrival counter
    float* partial = (float*)d_ws + 64;                  // [64..64+nblocks)
    hipMemsetAsync(counter, 0, sizeof(int), stream);     // graph-capture-safe

    cdl_fused<<<nblocks, THREADS, 0, stream>>>(outp, labp, partial, counter,
                                               (float*)d_out, nimg, inv_count);
}

// Round 5
// 28.542 us; speedup vs baseline: 3.4553x; 3.4553x over previous
//
#include <hip/hip_runtime.h>

// Contrast-depth loss:
//   d = out - label   (elementwise, [B,32,32] fp32)
//   loss = mean over (b, 8 neighbors, 30x30 centers) of
//          (d[y+dy][x+dx] - d[y][x])^2, centers y,x in [1,30]
//
// R5 design: per-lane 4x4 patch (2x2 centers), t<225 hoisted out of the image
// loop -> zero divergence, no LDS, no barriers, no shuffles in hot path.
// 32 immediate-offset loads per image off one base pointer; unroll 2 images;
// launch_bounds(256,2) gives the register budget for deep load batching.

#define THREADS 256
#define IPB 8   // images per block

__global__ __launch_bounds__(THREADS, 2) void cdl_partial(
    const float* __restrict__ outp,
    const float* __restrict__ labp,
    float* __restrict__ partial,
    int nimg)
{
    const int t = threadIdx.x;
    float acc = 0.f;

    if (t < 225) {   // thread-constant: no divergence inside the image loop
        const int qy = t / 15, qx = t - qy * 15;
        const long long base = (long long)blockIdx.x * IPB * 1024
                             + (2 * qy) * 32 + 2 * qx;   // even col -> 8B aligned
        const float* ob = outp + base;
        const float* lb = labp + base;
        const int n = (nimg - blockIdx.x * IPB < IPB) ? (nimg - blockIdx.x * IPB) : IPB;

        #pragma unroll 2
        for (int i = 0; i < n; ++i) {
            const float* o = ob + i * 1024;
            const float* l = lb + i * 1024;
            // ---- load phase: 32 independent 8B loads, immediate offsets ----
            float2 ov[4][2], lv[4][2];
            #pragma unroll
            for (int r = 0; r < 4; ++r) {
                ov[r][0] = *(const float2*)(o + r * 32);
                ov[r][1] = *(const float2*)(o + r * 32 + 2);
                lv[r][0] = *(const float2*)(l + r * 32);
                lv[r][1] = *(const float2*)(l + r * 32 + 2);
            }
            // ---- compute phase: pure register math ----
            float dd[4][4];
            #pragma unroll
            for (int r = 0; r < 4; ++r) {
                dd[r][0] = ov[r][0].x - lv[r][0].x;
                dd[r][1] = ov[r][0].y - lv[r][0].y;
                dd[r][2] = ov[r][1].x - lv[r][1].x;
                dd[r][3] = ov[r][1].y - lv[r][1].y;
            }
            #pragma unroll
            for (int cy = 1; cy <= 2; ++cy) {
                #pragma unroll
                for (int cx = 1; cx <= 2; ++cx) {
                    const float c = dd[cy][cx];
                    #pragma unroll
                    for (int ny = -1; ny <= 1; ++ny) {
                        #pragma unroll
                        for (int nx = -1; nx <= 1; ++nx) {
                            if (ny == 0 && nx == 0) continue;
                            const float v = dd[cy + ny][cx + nx] - c;
                            acc += v * v;
                        }
                    }
                }
            }
        }
    }

    // wave reduce, then 4 waves -> 1 value per block (fixed order, deterministic)
    #pragma unroll
    for (int off = 32; off; off >>= 1) acc += __shfl_down(acc, off, 64);
    __shared__ float red[4];
    const int lane = t & 63, wid = t >> 6;
    if (lane == 0) red[wid] = acc;
    __syncthreads();
    if (t == 0) partial[blockIdx.x] = red[0] + red[1] + red[2] + red[3];
}

__global__ __launch_bounds__(THREADS) void cdl_final(
    const float* __restrict__ partial,
    float* __restrict__ out,
    int np,
    float inv_count)
{
    __shared__ float red[THREADS / 64];
    const int t = threadIdx.x;
    float acc = 0.f;
    for (int i = t; i < np; i += THREADS) acc += partial[i];
    #pragma unroll
    for (int off = 32; off; off >>= 1) acc += __shfl_down(acc, off, 64);
    if ((t & 63) == 0) red[t >> 6] = acc;
    __syncthreads();
    if (t == 0) out[0] = (red[0] + red[1] + red[2] + red[3]) * inv_count;
}

extern "C" void kernel_launch(void* const* d_in, const int* in_sizes, int n_in,
                              void* d_out, int out_size, void* d_ws, size_t ws_size,
                              hipStream_t stream) {
    const float* outp = (const float*)d_in[0];
    const float* labp = (const float*)d_in[1];
    float* partial = (float*)d_ws;
    const int nimg = in_sizes[0] / 1024;               // B (H=W=32)
    const int nblocks = (nimg + IPB - 1) / IPB;        // 2048 for B=16384
    const float inv_count = 1.0f / ((float)nimg * 8.0f * 900.0f);

    cdl_partial<<<nblocks, THREADS, 0, stream>>>(outp, labp, partial, nimg);
    cdl_final<<<1, THREADS, 0, stream>>>(partial, (float*)d_out, nblocks, inv_count);
}